// Round 1
// baseline (10710.218 us; speedup 1.0000x reference)
//
#include <hip/hip_runtime.h>
#include <hip/hip_bf16.h>
#include <math.h>

// Problem constants
#define B 32
#define SENC 64
#define SDEC 32
#define HDIM 512
#define EDIM 512
#define VDIM 32000
#define G4 2048              // 4*H
#define BH (B*HDIM)          // 16384

// ---------------------------------------------------------------------------
// embed: gather emb rows for a token sequence  (n_tok blocks x 128 threads)
// ---------------------------------------------------------------------------
__global__ __launch_bounds__(128) void embed_kernel(const int* __restrict__ toks,
                                                    const float* __restrict__ emb,
                                                    float* __restrict__ out)
{
    int t = blockIdx.x;
    int id = toks[t];
    const float4* src = (const float4*)(emb + (size_t)id * EDIM);
    float4* dst = (float4*)(out + (size_t)t * EDIM);
    dst[threadIdx.x] = src[threadIdx.x];   // 128 * float4 = 512 floats
}

// ---------------------------------------------------------------------------
// Generic NT SGEMM: C[m,n] = sum_k A[m*K+k]*B[n*K+k] (+bias0[n]+bias1[n])
// block tile 128x64, 256 threads, 8x4 microtile. Requires M%128==0, N%64==0,
// K%16==0 (all call sites satisfy this).
// ---------------------------------------------------------------------------
__global__ __launch_bounds__(256) void gemm_nt(const float* __restrict__ A,
                                               const float* __restrict__ Bm,
                                               float* __restrict__ C,
                                               const float* __restrict__ bias0,
                                               const float* __restrict__ bias1,
                                               int M, int N, int K)
{
    __shared__ float As[16][128];
    __shared__ float Bs[16][64];
    int tid = threadIdx.x;
    int tx = tid & 15, ty = tid >> 4;
    int m0 = blockIdx.y * 128, n0 = blockIdx.x * 64;

    float acc[8][4];
    #pragma unroll
    for (int i = 0; i < 8; i++)
        #pragma unroll
        for (int j = 0; j < 4; j++) acc[i][j] = 0.f;

    int la_m = tid >> 1, la_k = (tid & 1) * 8;
    int lb_n = tid & 63, lb_k = (tid >> 6) * 4;
    const float* Aptr = A + (size_t)(m0 + la_m) * K + la_k;
    const float* Bptr = Bm + (size_t)(n0 + lb_n) * K + lb_k;

    for (int k0 = 0; k0 < K; k0 += 16) {
        float4 a1 = *(const float4*)(Aptr + k0);
        float4 a2 = *(const float4*)(Aptr + k0 + 4);
        float4 bv = *(const float4*)(Bptr + k0);
        As[la_k + 0][la_m] = a1.x; As[la_k + 1][la_m] = a1.y;
        As[la_k + 2][la_m] = a1.z; As[la_k + 3][la_m] = a1.w;
        As[la_k + 4][la_m] = a2.x; As[la_k + 5][la_m] = a2.y;
        As[la_k + 6][la_m] = a2.z; As[la_k + 7][la_m] = a2.w;
        Bs[lb_k + 0][lb_n] = bv.x; Bs[lb_k + 1][lb_n] = bv.y;
        Bs[lb_k + 2][lb_n] = bv.z; Bs[lb_k + 3][lb_n] = bv.w;
        __syncthreads();
        #pragma unroll
        for (int kk = 0; kk < 16; kk++) {
            float4 av1 = *(const float4*)&As[kk][ty * 8];
            float4 av2 = *(const float4*)&As[kk][ty * 8 + 4];
            float4 bvv = *(const float4*)&Bs[kk][tx * 4];
            float am[8] = {av1.x, av1.y, av1.z, av1.w, av2.x, av2.y, av2.z, av2.w};
            float bn[4] = {bvv.x, bvv.y, bvv.z, bvv.w};
            #pragma unroll
            for (int i = 0; i < 8; i++)
                #pragma unroll
                for (int j = 0; j < 4; j++)
                    acc[i][j] += am[i] * bn[j];
        }
        __syncthreads();
    }

    float bb[4] = {0.f, 0.f, 0.f, 0.f};
    int nc = n0 + tx * 4;
    if (bias0) {
        #pragma unroll
        for (int j = 0; j < 4; j++) bb[j] += bias0[nc + j];
    }
    if (bias1) {
        #pragma unroll
        for (int j = 0; j < 4; j++) bb[j] += bias1[nc + j];
    }
    #pragma unroll
    for (int i = 0; i < 8; i++) {
        int row = m0 + ty * 8 + i;
        float4 o = make_float4(acc[i][0] + bb[0], acc[i][1] + bb[1],
                               acc[i][2] + bb[2], acc[i][3] + bb[3]);
        *(float4*)(C + (size_t)row * N + nc) = o;
    }
}

// ---------------------------------------------------------------------------
// Encoder LSTM cell step: g = xg(precomputed x@Wih^T+bih+bhh) + h@Whh^T
// grid (32 jh-blocks of 16, 2 b-groups of 16), 256 threads.
// Thread owns (b, jh) and all 4 gates.
// ---------------------------------------------------------------------------
__global__ __launch_bounds__(256) void enc_cell(const float* __restrict__ xg,
                                                const float* __restrict__ Whh,
                                                const float* __restrict__ h_in,
                                                const float* __restrict__ c_in,
                                                float* __restrict__ h_out,
                                                float* __restrict__ c_out,
                                                float* __restrict__ seq_out,
                                                int t)
{
    __shared__ float hs[16 * 512];
    int bg = blockIdx.y;
    int bl = threadIdx.x & 15, q = threadIdx.x >> 4;
    int b = bg * 16 + bl;
    int jh = blockIdx.x * 16 + q;

    for (int i = threadIdx.x; i < 16 * 512; i += 256) {
        int bb = i >> 9, k = i & 511;
        hs[bb * 512 + ((k + bb) & 511)] = h_in[(bg * 16 + bb) * 512 + k];
    }
    __syncthreads();

    float acc[4];
    const float* wr[4];
    #pragma unroll
    for (int g = 0; g < 4; g++) {
        int row = g * 512 + jh;
        acc[g] = xg[(size_t)(b * SENC + t) * G4 + row];
        wr[g] = Whh + (size_t)row * 512;
    }
    const float* hrow = hs + bl * 512;
    for (int k = 0; k < 512; k += 4) {
        float hv[4];
        #pragma unroll
        for (int u = 0; u < 4; u++) hv[u] = hrow[(k + u + bl) & 511];
        #pragma unroll
        for (int g = 0; g < 4; g++) {
            float4 w = *(const float4*)(wr[g] + k);
            acc[g] += w.x * hv[0] + w.y * hv[1] + w.z * hv[2] + w.w * hv[3];
        }
    }
    float ig = 1.f / (1.f + expf(-acc[0]));
    float fg = 1.f / (1.f + expf(-acc[1]));
    float gg = tanhf(acc[2]);
    float og = 1.f / (1.f + expf(-acc[3]));
    float cn = fg * c_in[b * 512 + jh] + ig * gg;
    float hn = og * tanhf(cn);
    c_out[b * 512 + jh] = cn;
    h_out[b * 512 + jh] = hn;
    seq_out[(size_t)(b * SENC + t) * 512 + jh] = hn;
}

// ---------------------------------------------------------------------------
// Decoder LSTM cell step: g = inp@Wih^T + bih + h@Whh^T + bhh
// ---------------------------------------------------------------------------
__global__ __launch_bounds__(256) void dec_cell(const float* __restrict__ inp,
                                                const float* __restrict__ Wih,
                                                const float* __restrict__ Whh,
                                                const float* __restrict__ bih,
                                                const float* __restrict__ bhh,
                                                const float* __restrict__ h_in,
                                                const float* __restrict__ c_in,
                                                float* __restrict__ h_out,
                                                float* __restrict__ c_out,
                                                float* __restrict__ h2buf,
                                                int t)
{
    __shared__ float hs[16 * 512];
    __shared__ float is_[16 * 512];
    int bg = blockIdx.y;
    int bl = threadIdx.x & 15, q = threadIdx.x >> 4;
    int b = bg * 16 + bl;
    int jh = blockIdx.x * 16 + q;

    for (int i = threadIdx.x; i < 16 * 512; i += 256) {
        int bb = i >> 9, k = i & 511;
        int addr = bb * 512 + ((k + bb) & 511);
        hs[addr] = h_in[(bg * 16 + bb) * 512 + k];
        is_[addr] = inp[(bg * 16 + bb) * 512 + k];
    }
    __syncthreads();

    float acc[4];
    const float* wih[4];
    const float* whh[4];
    #pragma unroll
    for (int g = 0; g < 4; g++) {
        int row = g * 512 + jh;
        acc[g] = bih[row] + bhh[row];
        wih[g] = Wih + (size_t)row * 512;
        whh[g] = Whh + (size_t)row * 512;
    }
    const float* hrow = hs + bl * 512;
    const float* irow = is_ + bl * 512;
    for (int k = 0; k < 512; k += 4) {
        float hv[4], iv[4];
        #pragma unroll
        for (int u = 0; u < 4; u++) {
            int idx = (k + u + bl) & 511;
            hv[u] = hrow[idx];
            iv[u] = irow[idx];
        }
        #pragma unroll
        for (int g = 0; g < 4; g++) {
            float4 wi = *(const float4*)(wih[g] + k);
            float4 wh = *(const float4*)(whh[g] + k);
            acc[g] += wi.x * iv[0] + wi.y * iv[1] + wi.z * iv[2] + wi.w * iv[3];
            acc[g] += wh.x * hv[0] + wh.y * hv[1] + wh.z * hv[2] + wh.w * hv[3];
        }
    }
    float ig = 1.f / (1.f + expf(-acc[0]));
    float fg = 1.f / (1.f + expf(-acc[1]));
    float gg = tanhf(acc[2]);
    float og = 1.f / (1.f + expf(-acc[3]));
    float cn = fg * c_in[b * 512 + jh] + ig * gg;
    float hn = og * tanhf(cn);
    c_out[b * 512 + jh] = cn;
    h_out[b * 512 + jh] = hn;
    if (h2buf) h2buf[(size_t)(b * SDEC + t) * 512 + jh] = hn;
}

// ---------------------------------------------------------------------------
// Attention ('general') + combine, one block per batch element.
// ---------------------------------------------------------------------------
__device__ __forceinline__ float allreduce64(float v)
{
    #pragma unroll
    for (int m = 1; m < 64; m <<= 1) v += __shfl_xor(v, m);
    return v;
}

__global__ __launch_bounds__(256) void attn_comb(const float* __restrict__ h2,
                                                 const float* __restrict__ enc_out,
                                                 const int* __restrict__ xs,
                                                 const int* __restrict__ ys,
                                                 const float* __restrict__ emb,
                                                 const float* __restrict__ attn_W,
                                                 const float* __restrict__ comb_W,
                                                 float* __restrict__ inp_out,
                                                 int t)
{
    __shared__ float h2s[512];
    __shared__ float xc[1024];   // [xe | ctx]
    __shared__ float hid[512];
    __shared__ float pw[64];
    __shared__ float aw[64];
    int b = blockIdx.x;
    int tid = threadIdx.x;
    int lane = tid & 63, wv = tid >> 6;
    int yt = ys[b * SDEC + t];

    for (int i = tid; i < 512; i += 256) {
        h2s[i] = h2[b * 512 + i];
        xc[i] = emb[(size_t)yt * EDIM + i];
    }
    __syncthreads();

    // hid = h2 @ attn_W^T   (wave-per-output, shuffle reduce)
    for (int e = wv; e < 512; e += 4) {
        const float* row = attn_W + (size_t)e * 512;
        float pp = 0.f;
        #pragma unroll
        for (int i = 0; i < 8; i++) pp += h2s[lane + 64 * i] * row[lane + 64 * i];
        pp = allreduce64(pp);
        if (lane == 0) hid[e] = pp;
    }
    __syncthreads();

    // pw[s] = hid . enc_out[b,s,:] - neg
    for (int s = wv; s < SENC; s += 4) {
        const float* row = enc_out + (size_t)(b * SENC + s) * 512;
        float pp = 0.f;
        #pragma unroll
        for (int i = 0; i < 8; i++) pp += hid[lane + 64 * i] * row[lane + 64 * i];
        pp = allreduce64(pp);
        if (lane == 0)
            pw[s] = pp - ((xs[b * SENC + s] > 0) ? 0.f : 1e20f);
    }
    __syncthreads();

    // softmax over 64 (single wave)
    if (tid < 64) {
        float v = pw[tid];
        float m = v;
        #pragma unroll
        for (int o = 1; o < 64; o <<= 1) m = fmaxf(m, __shfl_xor(m, o));
        float ex = expf(v - m);
        float sm = ex;
        #pragma unroll
        for (int o = 1; o < 64; o <<= 1) sm += __shfl_xor(sm, o);
        aw[tid] = ex / sm;
    }
    __syncthreads();

    // ctx[e] = sum_s aw[s] * enc_out[b,s,e]  (coalesced over e)
    for (int e = tid; e < 512; e += 256) {
        float s = 0.f;
        for (int ss = 0; ss < SENC; ss++)
            s += aw[ss] * enc_out[(size_t)(b * SENC + ss) * 512 + e];
        xc[512 + e] = s;
    }
    __syncthreads();

    // inp = tanh([xe,ctx] @ comb_W^T)
    for (int e = wv; e < 512; e += 4) {
        const float* row = comb_W + (size_t)e * 1024;
        float pp = 0.f;
        #pragma unroll
        for (int i = 0; i < 16; i++) pp += xc[lane + 64 * i] * row[lane + 64 * i];
        pp = allreduce64(pp);
        if (lane == 0) inp_out[b * 512 + e] = tanhf(pp);
    }
}

// ---------------------------------------------------------------------------
// argmax over scores[m, 1:], lowest index on ties; preds[m] = index (float)
// ---------------------------------------------------------------------------
__global__ __launch_bounds__(256) void argmax_kernel(const float* __restrict__ scores,
                                                     float* __restrict__ preds)
{
    __shared__ float sv[256];
    __shared__ int si[256];
    int m = blockIdx.x;
    const float* row = scores + (size_t)m * VDIM;
    float best = -3.4e38f;
    int bi = 0x7fffffff;
    for (int v = 1 + (int)threadIdx.x; v < VDIM; v += 256) {
        float val = row[v];
        if (val > best) { best = val; bi = v; }   // ascending scan → lowest idx kept
    }
    sv[threadIdx.x] = best;
    si[threadIdx.x] = bi;
    __syncthreads();
    for (int s = 128; s > 0; s >>= 1) {
        if ((int)threadIdx.x < s) {
            float ov = sv[threadIdx.x + s];
            int oi = si[threadIdx.x + s];
            if (ov > sv[threadIdx.x] ||
                (ov == sv[threadIdx.x] && oi < si[threadIdx.x])) {
                sv[threadIdx.x] = ov;
                si[threadIdx.x] = oi;
            }
        }
        __syncthreads();
    }
    if (threadIdx.x == 0) preds[m] = (float)si[0];
}

// ---------------------------------------------------------------------------
extern "C" void kernel_launch(void* const* d_in, const int* in_sizes, int n_in,
                              void* d_out, int out_size, void* d_ws, size_t ws_size,
                              hipStream_t stream)
{
    const int* xs = (const int*)d_in[0];
    const int* ys = (const int*)d_in[1];
    const float* emb = (const float*)d_in[2];
    const float* W[16];
    for (int i = 0; i < 16; i++) W[i] = (const float*)d_in[3 + i];
    // enc layer l: W[l*4+{0:Wih,1:Whh,2:bih,3:bhh}] ; dec layer l: W[8+l*4+...]
    const float* attn_W = (const float*)d_in[19];
    const float* comb_W = (const float*)d_in[20];
    float* out = (float*)d_out;
    float* ws = (float*)d_ws;

    // workspace layout (floats)
    float* xemb  = ws;                   // 2048*512      = 1,048,576
    float* xg    = xemb + 1048576;       // 2048*2048     = 4,194,304
    float* l0out = xg + 4194304;         // 2048*512
    float* l1out = l0out + 1048576;      // 2048*512  (enc_out)
    float* ench  = l1out + 1048576;      // 2 * BH
    float* encc  = ench + 2 * BH;        // 2 * BH
    float* dech  = encc + 2 * BH;        // 2 * 2 * BH (parity, layer)
    float* decc  = dech + 4 * BH;        // 2 * 2 * BH
    // overlay decoder buffers onto xg (dead after encoder)
    float* h2buf = xg;                   // 1024*512 = 524,288
    float* inpbuf = xg + 524288;         // 32*512

    // ---- Encoder ----
    embed_kernel<<<B * SENC, 128, 0, stream>>>(xs, emb, xemb);
    for (int l = 0; l < 2; l++) {
        const float* Wih = W[l * 4 + 0];
        const float* Whh = W[l * 4 + 1];
        const float* bih = W[l * 4 + 2];
        const float* bhh = W[l * 4 + 3];
        const float* Ain = (l == 0) ? xemb : l0out;
        float* lout = (l == 0) ? l0out : l1out;
        gemm_nt<<<dim3(G4 / 64, (B * SENC) / 128), 256, 0, stream>>>(
            Ain, Wih, xg + (l == 0 ? 0 : 0), bih, bhh, B * SENC, G4, 512);
        hipMemsetAsync(ench, 0, 2 * BH * sizeof(float), stream);
        hipMemsetAsync(encc, 0, 2 * BH * sizeof(float), stream);
        int p = 0;
        for (int t = 0; t < SENC; t++) {
            enc_cell<<<dim3(32, 2), 256, 0, stream>>>(
                xg, Whh, ench + p * BH, encc + p * BH,
                ench + (1 - p) * BH, encc + (1 - p) * BH, lout, t);
            p ^= 1;
        }
        // p == 0 after 64 steps; final states in slot p
        hipMemcpyAsync(dech + l * BH, ench + p * BH, BH * sizeof(float),
                       hipMemcpyDeviceToDevice, stream);
        hipMemcpyAsync(decc + l * BH, encc + p * BH, BH * sizeof(float),
                       hipMemcpyDeviceToDevice, stream);
    }

    // NOTE: xg region is reused from here on (h2buf/inpbuf overlay).
    // ---- Decoder ----
    int p = 0;   // parity stride = 2*BH; layer stride = BH
    for (int t = 0; t < SDEC; t++) {
        int q = 1 - p;
        attn_comb<<<B, 256, 0, stream>>>(
            dech + p * 2 * BH + BH, l1out, xs, ys, emb, attn_W, comb_W, inpbuf, t);
        dec_cell<<<dim3(32, 2), 256, 0, stream>>>(
            inpbuf, W[8], W[9], W[10], W[11],
            dech + p * 2 * BH, decc + p * 2 * BH,
            dech + q * 2 * BH, decc + q * 2 * BH, (float*)nullptr, t);
        dec_cell<<<dim3(32, 2), 256, 0, stream>>>(
            dech + q * 2 * BH, W[12], W[13], W[14], W[15],
            dech + p * 2 * BH + BH, decc + p * 2 * BH + BH,
            dech + q * 2 * BH + BH, decc + q * 2 * BH + BH, h2buf, t);
        p = q;
    }

    // ---- Output projection + argmax ----
    // scores[m, v], m = b*SDEC + t, laid out directly into d_out after preds
    gemm_nt<<<dim3(VDIM / 64, (B * SDEC) / 128), 256, 0, stream>>>(
        h2buf, emb, out + B * SDEC, nullptr, nullptr, B * SDEC, VDIM, 512);
    argmax_kernel<<<B * SDEC, 256, 0, stream>>>(out + B * SDEC, out);
}